// Round 1
// baseline (15.526 us; speedup 1.0000x reference)
//
#include <hip/hip_runtime.h>

#define NB 8
#define SS 43
#define NQ 13
#define DD 608
#define KK 4

__global__ __launch_bounds__(64) void imp_enc_kernel(
    const float* __restrict__ x, const float* __restrict__ scores,
    const float* __restrict__ Wff, const float* __restrict__ bff,
    float* __restrict__ out)
{
    const int blk  = blockIdx.x;          // 0 .. B*NQ-1
    const int b    = blk / NQ;
    const int i    = blk % NQ;
    const int lane = threadIdx.x;         // 0 .. 63

    // ---- top-4 of scores[b, i, 0:13] (redundant in all lanes; 13 broadcast loads) ----
    float v[NQ];
    const float* srow = scores + (size_t)b * SS * SS + (size_t)i * SS;
    #pragma unroll
    for (int j = 0; j < NQ; ++j) v[j] = srow[j];

    int idx[KK];
    unsigned sel = 0;
    #pragma unroll
    for (int k = 0; k < KK; ++k) {
        float best = -INFINITY;
        int bj = 0;
        #pragma unroll
        for (int j = 0; j < NQ; ++j) {
            // strict '>' => lowest index wins ties, matching jax.lax.top_k
            if (!((sel >> j) & 1u) && v[j] > best) { best = v[j]; bj = j; }
        }
        sel |= 1u << bj;
        idx[k] = bj;
    }

    // ---- cooperative dot products: self row vs W_top, 4 gathered rows vs W_bot ----
    const float* xs = x + ((size_t)b * SS + i) * DD;
    const float* xg[KK];
    #pragma unroll
    for (int k = 0; k < KK; ++k) xg[k] = x + ((size_t)b * SS + idx[k]) * DD;

    float accS[4] = {0.f, 0.f, 0.f, 0.f};
    float accG[KK][4] = {};

    for (int e = lane; e < DD; e += 64) {
        float  xv = xs[e];
        float4 wt = *(const float4*)(Wff + (size_t)e * 4);          // W_top row
        float4 wb = *(const float4*)(Wff + (size_t)(e + DD) * 4);   // W_bot row
        accS[0] += xv * wt.x;
        accS[1] += xv * wt.y;
        accS[2] += xv * wt.z;
        accS[3] += xv * wt.w;
        #pragma unroll
        for (int k = 0; k < KK; ++k) {
            float gv = xg[k][e];
            accG[k][0] += gv * wb.x;
            accG[k][1] += gv * wb.y;
            accG[k][2] += gv * wb.z;
            accG[k][3] += gv * wb.w;
        }
    }

    // ---- butterfly reduce across the wave (result lands in every lane) ----
    #pragma unroll
    for (int off = 32; off > 0; off >>= 1) {
        #pragma unroll
        for (int c = 0; c < 4; ++c) accS[c] += __shfl_xor(accS[c], off, 64);
        #pragma unroll
        for (int k = 0; k < KK; ++k)
            #pragma unroll
            for (int c = 0; c < 4; ++c) accG[k][c] += __shfl_xor(accG[k][c], off, 64);
    }

    // ---- write 13*4 output row: base [1,0,0,0], selected j get vals ----
    if (lane < NQ * 4) {
        const int j = lane >> 2;
        const int c = lane & 3;
        float val = (c == 0) ? 1.0f : 0.0f;
        #pragma unroll
        for (int k = 0; k < KK; ++k)
            if (j == idx[k]) val = accS[c] + accG[k][c] + bff[c];
        out[(size_t)blk * (NQ * 4) + lane] = val;
    }
}

extern "C" void kernel_launch(void* const* d_in, const int* in_sizes, int n_in,
                              void* d_out, int out_size, void* d_ws, size_t ws_size,
                              hipStream_t stream) {
    const float* x      = (const float*)d_in[0];
    const float* scores = (const float*)d_in[1];
    const float* Wff    = (const float*)d_in[2];
    const float* bff    = (const float*)d_in[3];
    float* out = (float*)d_out;

    imp_enc_kernel<<<NB * NQ, 64, 0, stream>>>(x, scores, Wff, bff, out);
}

// Round 2
// 9.646 us; speedup vs baseline: 1.6096x; 1.6096x over previous
//
#include <hip/hip_runtime.h>

#define NB 8
#define SS 43
#define NQ 13
#define DD 608
#define KK 4
#define NF4 (DD / 4)   // 152 float4 per x-row

__global__ __launch_bounds__(64) void imp_enc_kernel(
    const float* __restrict__ x, const float* __restrict__ scores,
    const float* __restrict__ Wff, const float* __restrict__ bff,
    float* __restrict__ out)
{
    const int blk  = blockIdx.x;          // 0 .. B*NQ-1
    const int b    = blk / NQ;
    const int i    = blk % NQ;
    const int lane = threadIdx.x;         // 0 .. 63

    const float4* W4  = (const float4*)Wff;                          // row e = W4[e]
    const float4* xs4 = (const float4*)(x + ((size_t)b * SS + i) * DD);

    // early independent loads
    float4 bias = *(const float4*)bff;
    const float* srow = scores + (size_t)b * SS * SS + (size_t)i * SS;
    float myv = (lane < NQ) ? srow[lane] : -INFINITY;   // one coalesced load

    // ---- loop A: self-row dot W_top (independent of top-k; issues first) ----
    float accS[4] = {0.f, 0.f, 0.f, 0.f};
    #pragma unroll
    for (int it = 0; it < 3; ++it) {
        const int f = lane + it * 64;
        if (f < NF4) {
            float4 xv = xs4[f];
            const float xe[4] = {xv.x, xv.y, xv.z, xv.w};
            #pragma unroll
            for (int u = 0; u < 4; ++u) {
                float4 wt = W4[f * 4 + u];
                accS[0] += xe[u] * wt.x;
                accS[1] += xe[u] * wt.y;
                accS[2] += xe[u] * wt.z;
                accS[3] += xe[u] * wt.w;
            }
        }
    }

    // ---- lane-parallel top-4 of scores[b,i,0:13] ----
    // rank = #elements strictly better (ties -> lower index wins, matches lax.top_k)
    int rank = 0;
    #pragma unroll
    for (int m = 0; m < NQ; ++m) {
        float vm = __shfl(myv, m, 64);
        if (vm > myv || (vm == myv && m < lane)) ++rank;
    }
    int idx[KK];
    #pragma unroll
    for (int k = 0; k < KK; ++k) {
        unsigned long long msk = __ballot(lane < NQ && rank == k);
        idx[k] = (int)__ffsll(msk) - 1;   // wave-uniform
    }

    // ---- loop B: 4 gathered rows dot W_bot ----
    const float4* xg4[KK];
    #pragma unroll
    for (int k = 0; k < KK; ++k)
        xg4[k] = (const float4*)(x + ((size_t)b * SS + idx[k]) * DD);

    float accG[KK][4] = {};
    #pragma unroll
    for (int it = 0; it < 3; ++it) {
        const int f = lane + it * 64;
        if (f < NF4) {
            float4 gv[KK];
            #pragma unroll
            for (int k = 0; k < KK; ++k) gv[k] = xg4[k][f];
            #pragma unroll
            for (int u = 0; u < 4; ++u) {
                float4 wb = W4[DD + f * 4 + u];
                #pragma unroll
                for (int k = 0; k < KK; ++k) {
                    const float ge[4] = {gv[k].x, gv[k].y, gv[k].z, gv[k].w};
                    accG[k][0] += ge[u] * wb.x;
                    accG[k][1] += ge[u] * wb.y;
                    accG[k][2] += ge[u] * wb.z;
                    accG[k][3] += ge[u] * wb.w;
                }
            }
        }
    }

    // ---- butterfly reduce across the wave (result in every lane) ----
    #pragma unroll
    for (int off = 32; off > 0; off >>= 1) {
        #pragma unroll
        for (int c = 0; c < 4; ++c) accS[c] += __shfl_xor(accS[c], off, 64);
        #pragma unroll
        for (int k = 0; k < KK; ++k)
            #pragma unroll
            for (int c = 0; c < 4; ++c) accG[k][c] += __shfl_xor(accG[k][c], off, 64);
    }

    // ---- write 13*4 outputs; avoid runtime register-array indexing (rule #20) ----
    if (lane < NQ * 4) {
        const int j = lane >> 2;
        const int c = lane & 3;
        // explicit select chains instead of acc[c]
        const float vS = (c & 2) ? ((c & 1) ? accS[3] : accS[2])
                                 : ((c & 1) ? accS[1] : accS[0]);
        const float bc = (c & 2) ? ((c & 1) ? bias.w : bias.z)
                                 : ((c & 1) ? bias.y : bias.x);
        float val = (c == 0) ? 1.0f : 0.0f;
        #pragma unroll
        for (int k = 0; k < KK; ++k) {
            const float vG = (c & 2) ? ((c & 1) ? accG[k][3] : accG[k][2])
                                     : ((c & 1) ? accG[k][1] : accG[k][0]);
            if (j == idx[k]) val = vS + vG + bc;
        }
        out[(size_t)blk * (NQ * 4) + lane] = val;
    }
}

extern "C" void kernel_launch(void* const* d_in, const int* in_sizes, int n_in,
                              void* d_out, int out_size, void* d_ws, size_t ws_size,
                              hipStream_t stream) {
    const float* x      = (const float*)d_in[0];
    const float* scores = (const float*)d_in[1];
    const float* Wff    = (const float*)d_in[2];
    const float* bff    = (const float*)d_in[3];
    float* out = (float*)d_out;

    imp_enc_kernel<<<NB * NQ, 64, 0, stream>>>(x, scores, Wff, bff, out);
}

// Round 3
// 9.376 us; speedup vs baseline: 1.6559x; 1.0288x over previous
//
#include <hip/hip_runtime.h>

#define NB 8
#define SS 43
#define NQ 13
#define DD 608
#define KK 4
#define NF4 (DD / 4)   // 152 float4 per x-row

__global__ __launch_bounds__(256) void imp_enc_kernel(
    const float* __restrict__ x, const float* __restrict__ scores,
    const float* __restrict__ Wff, const float* __restrict__ bff,
    float* __restrict__ out)
{
    const int bi   = blockIdx.x;            // 0 .. B*NQ-1
    const int b    = bi / NQ;
    const int i    = bi % NQ;
    const int k    = threadIdx.x >> 6;      // wave id 0..3 = which gather this wave owns
    const int lane = threadIdx.x & 63;

    const float4* W4  = (const float4*)Wff;     // W4[e] = row e (4 cols); W_bot row e = W4[DD+e]
    const float4* xs4 = (const float4*)(x + ((size_t)b * SS + i) * DD);

    // early independent loads
    float4 bias = *(const float4*)bff;
    const float* srow = scores + ((size_t)b * SS + i) * SS;
    float myv = (lane < NQ) ? srow[lane] : -INFINITY;   // coalesced, lane j holds score j

    // ---- self-row dot W_top (independent of top-k; hides score-load latency) ----
    float accS[4] = {0.f, 0.f, 0.f, 0.f};
    #pragma unroll
    for (int it = 0; it < 3; ++it) {
        const int f = lane + it * 64;
        if (f < NF4) {
            float4 xv = xs4[f];
            const float xe[4] = {xv.x, xv.y, xv.z, xv.w};
            #pragma unroll
            for (int u = 0; u < 4; ++u) {
                float4 wt = W4[f * 4 + u];
                accS[0] += xe[u] * wt.x;
                accS[1] += xe[u] * wt.y;
                accS[2] += xe[u] * wt.z;
                accS[3] += xe[u] * wt.w;
            }
        }
    }

    // ---- lane-parallel top-4 (each wave computes it redundantly; no barrier) ----
    // rank = #elements strictly better; ties -> lower index (matches lax.top_k)
    int rank = 0;
    #pragma unroll
    for (int m = 0; m < NQ; ++m) {
        float vm = __shfl(myv, m, 64);
        if (vm > myv || (vm == myv && m < lane)) ++rank;
    }
    int idx[KK];
    #pragma unroll
    for (int kk = 0; kk < KK; ++kk) {
        unsigned long long msk = __ballot(lane < NQ && rank == kk);
        idx[kk] = (int)__ffsll(msk) - 1;   // wave-uniform
    }

    // ---- this wave's gathered row dot W_bot ----
    const float4* xg4 = (const float4*)(x + ((size_t)b * SS + idx[k]) * DD);
    float accG[4] = {0.f, 0.f, 0.f, 0.f};
    #pragma unroll
    for (int it = 0; it < 3; ++it) {
        const int f = lane + it * 64;
        if (f < NF4) {
            float4 gv = xg4[f];
            const float ge[4] = {gv.x, gv.y, gv.z, gv.w};
            #pragma unroll
            for (int u = 0; u < 4; ++u) {
                float4 wb = W4[DD + f * 4 + u];
                accG[0] += ge[u] * wb.x;
                accG[1] += ge[u] * wb.y;
                accG[2] += ge[u] * wb.z;
                accG[3] += ge[u] * wb.w;
            }
        }
    }

    // ---- butterfly reduce 8 values across the wave ----
    #pragma unroll
    for (int off = 32; off > 0; off >>= 1) {
        #pragma unroll
        for (int c = 0; c < 4; ++c) {
            accS[c] += __shfl_xor(accS[c], off, 64);
            accG[c] += __shfl_xor(accG[c], off, 64);
        }
    }

    // ---- write: wave k owns row j=idx[k]; wave 0 also writes base rows ----
    if (lane < NQ * 4) {
        const int j = lane >> 2;
        const int c = lane & 3;
        // explicit select chains (no runtime register-array indexing, rule #20)
        const float vS = (c & 2) ? ((c & 1) ? accS[3] : accS[2])
                                 : ((c & 1) ? accS[1] : accS[0]);
        const float vG = (c & 2) ? ((c & 1) ? accG[3] : accG[2])
                                 : ((c & 1) ? accG[1] : accG[0]);
        const float bc = (c & 2) ? ((c & 1) ? bias.w : bias.z)
                                 : ((c & 1) ? bias.y : bias.x);
        const bool sel = (j == idx[0]) | (j == idx[1]) | (j == idx[2]) | (j == idx[3]);
        float* orow = out + (size_t)bi * (NQ * 4);
        if (j == idx[k]) {
            orow[lane] = vS + vG + bc;              // this wave's selected row
        } else if (k == 0 && !sel) {
            orow[lane] = (c == 0) ? 1.0f : 0.0f;    // base rows, disjoint addresses
        }
    }
}

extern "C" void kernel_launch(void* const* d_in, const int* in_sizes, int n_in,
                              void* d_out, int out_size, void* d_ws, size_t ws_size,
                              hipStream_t stream) {
    const float* x      = (const float*)d_in[0];
    const float* scores = (const float*)d_in[1];
    const float* Wff    = (const float*)d_in[2];
    const float* bff    = (const float*)d_in[3];
    float* out = (float*)d_out;

    imp_enc_kernel<<<NB * NQ, 256, 0, stream>>>(x, scores, Wff, bff, out);
}